// Round 15
// baseline (232.783 us; speedup 1.0000x reference)
//
#include <hip/hip_runtime.h>
#include <math.h>

#define BATCH 8
#define NPTS  1024
#define KNN   20
#define BNF   0.99999500003749937f  // 1/sqrt(1+1e-5)

typedef short bf16x8 __attribute__((ext_vector_type(8)));
typedef float f32x4  __attribute__((ext_vector_type(4)));
typedef float f32x16 __attribute__((ext_vector_type(16)));

__device__ __forceinline__ float leakyf(float x){ return x >= 0.f ? x : 0.2f*x; }

__device__ __forceinline__ void atomicMaxFloat(float* addr, float val){
  if (val >= 0.f) atomicMax((int*)addr, __float_as_int(val));
  else            atomicMin((unsigned int*)addr, __float_as_uint(val));
}

__device__ __forceinline__ unsigned short f2bf(float x){
  unsigned u = __float_as_uint(x);
  unsigned r = (u + 0x7FFFu + ((u >> 16) & 1u)) >> 16;   // RNE (no NaN/inf in data)
  return (unsigned short)r;
}
__device__ __forceinline__ float bf2f(unsigned short h){
  return __uint_as_float(((unsigned)h) << 16);
}

// monotone f32 -> u32 key (exact order-preserving)
__device__ __forceinline__ unsigned ordkey(float x){
  unsigned u = __float_as_uint(x);
  unsigned mask = (unsigned)(((int)u) >> 31) | 0x80000000u;
  return u ^ mask;
}

// swizzled 16B-slot index within a 64B row (read side); write side pre-swizzles
// the GLOBAL source address so the LDS dest stays linear for global_load_lds.
__device__ __forceinline__ int swz(int q, int row){ return q ^ ((row >> 1) & 3); }

// async global->LDS, 16B per lane, dest = wave-uniform base + lane*16
__device__ __forceinline__ void gload_lds16(const void* g, void* l){
  __builtin_amdgcn_global_load_lds(
      (const __attribute__((address_space(1))) unsigned int*)g,
      (__attribute__((address_space(3))) unsigned int*)l, 16, 0, 0);
}

// =====================================================================
// k_prep: weight pack+split, pool init, x transpose, EC1 U/V projection.
// =====================================================================
__device__ __forceinline__ void split4store(float v0, float v1, float v2, float v3,
                                            unsigned short* hi, unsigned short* lo, long off){
  unsigned short h0=f2bf(v0), h1=f2bf(v1), h2=f2bf(v2), h3=f2bf(v3);
  *(ushort4*)(hi+off) = make_ushort4(h0,h1,h2,h3);
  *(ushort4*)(lo+off) = make_ushort4(f2bf(v0-bf2f(h0)), f2bf(v1-bf2f(h1)),
                                     f2bf(v2-bf2f(h2)), f2bf(v3-bf2f(h3)));
}

__global__ __launch_bounds__(256) void k_prep(
    const float* __restrict__ x,  const float* __restrict__ W1,
    const float* __restrict__ W2, const float* __restrict__ W3,
    const float* __restrict__ W4, const float* __restrict__ W2m,
    const float* __restrict__ W5,
    unsigned short* __restrict__ w2h, unsigned short* __restrict__ w2l,
    unsigned short* __restrict__ w3h, unsigned short* __restrict__ w3l,
    unsigned short* __restrict__ w4h, unsigned short* __restrict__ w4l,
    unsigned short* __restrict__ wmh, unsigned short* __restrict__ wml,
    unsigned short* __restrict__ w5h, unsigned short* __restrict__ w5l,
    float* __restrict__ p1, float* __restrict__ p2, float* __restrict__ xt,
    float* __restrict__ UV)
{
  int u = blockIdx.x*256 + threadIdx.x;
  if (u < 2048){                                   // S1: W2 pack+split
    int o = u >> 4, c = (u & 15) * 4;
    const float* s = (o < 64) ? (W2 + o*128 + c) : (W2 + (o-64)*128 + 64 + c);
    float4 v = *(const float4*)s;
    split4store(v.x,v.y,v.z,v.w, w2h,w2l, (long)o*64 + c);
    return;
  }
  u -= 2048;
  if (u < 16384){                                  // S2: W3 fold+split
    int o = u >> 5, c = (u & 31) * 4;
    const float* s = (o < 256) ? (W3 + o*512 + c) : (W3 + (o-256)*512 + 256 + c);
    float4 a = *(const float4*)s;
    float4 b = *(const float4*)(s + 128);
    split4store(a.x+b.x, a.y+b.y, a.z+b.z, a.w+b.w, w3h,w3l, (long)o*128 + c);
    return;
  }
  u -= 16384;
  if (u < 32768){                                  // S3: W4 pack+split
    int o = u >> 6, c = (u & 63) * 4;
    const float* s = (o < 256) ? (W4 + o*512 + c) : (W4 + (o-256)*512 + 256 + c);
    float4 v = *(const float4*)s;
    split4store(v.x,v.y,v.z,v.w, w4h,w4l, (long)o*256 + c);
    return;
  }
  u -= 32768;
  if (u < 32768){                                  // S4: W2m split
    int r = u >> 5, c = (u & 31) * 4;
    float4 v = *(const float4*)(W2m + (long)r*128 + c);
    split4store(v.x,v.y,v.z,v.w, wmh,wml, (long)r*128 + c);
    return;
  }
  u -= 32768;
  if (u < 131072){                                 // S5: W5 split
    int r = u >> 7, c = (u & 127) * 4;
    float4 v = *(const float4*)(W5 + (long)r*512 + c);
    split4store(v.x,v.y,v.z,v.w, w5h,w5l, (long)r*512 + c);
    return;
  }
  u -= 131072;
  if (u < 4096){                                   // S6: pool init
    float4 ninf = make_float4(-INFINITY,-INFINITY,-INFINITY,-INFINITY);
    if (u < 2048) *(float4*)(p1 + u*4) = ninf;
    else          *(float4*)(p2 + (u-2048)*4) = ninf;
    return;
  }
  u -= 4096;
  if (u < 6144){                                   // S7: transpose x -> xt
    int b = u / 768, rem = u % 768;
    int c = rem >> 8, n0 = (rem & 255) * 4;
    float4 v = *(const float4*)(x + ((long)b*3 + c)*NPTS + n0);
    float* o = xt + (long)b*NPTS*3;
    o[(n0+0)*3 + c] = v.x; o[(n0+1)*3 + c] = v.y;
    o[(n0+2)*3 + c] = v.z; o[(n0+3)*3 + c] = v.w;
    return;
  }
  u -= 6144;
  {                                                // S8: EC1 U/V from x directly
    int p = u >> 7, o = u & 127;
    int b = p >> 10, n = p & 1023;
    const float* xb = x + (long)b*3*NPTS + n;
    float x0 = xb[0], x1 = xb[NPTS], x2 = xb[2*NPTS];
    const float* w = (o < 64) ? (W1 + o*6) : (W1 + (o-64)*6 + 3);
    UV[(long)p*128 + o] = w[0]*x0 + w[1]*x1 + w[2]*x2;
  }
}

// ================= top-20 selection (exact: value desc, index asc) =================
__device__ __forceinline__ unsigned wave_max_u32(unsigned x){
  unsigned t;
  t = (unsigned)__builtin_amdgcn_update_dpp((int)x, (int)x, 0x111, 0xf, 0xf, false); x = x > t ? x : t;
  t = (unsigned)__builtin_amdgcn_update_dpp((int)x, (int)x, 0x112, 0xf, 0xf, false); x = x > t ? x : t;
  t = (unsigned)__builtin_amdgcn_update_dpp((int)x, (int)x, 0x114, 0xf, 0xf, false); x = x > t ? x : t;
  t = (unsigned)__builtin_amdgcn_update_dpp((int)x, (int)x, 0x118, 0xf, 0xf, false); x = x > t ? x : t;
  t = (unsigned)__builtin_amdgcn_update_dpp((int)x, (int)x, 0x142, 0xa, 0xf, false); x = x > t ? x : t;
  t = (unsigned)__builtin_amdgcn_update_dpp((int)x, (int)x, 0x143, 0xc, 0xf, false); x = x > t ? x : t;
  return (unsigned)__builtin_amdgcn_readlane((int)x, 63);
}

__device__ __forceinline__ void topk_select(unsigned long long* sk,
                                            unsigned long long* lds,
                                            int* out, int lane)
{
  #define CE(a,b) { unsigned long long ka=sk[a], kb=sk[b]; bool sw=ka<kb; sk[a]=sw?kb:ka; sk[b]=sw?ka:kb; }
  CE(0,1) CE(2,3) CE(4,5) CE(6,7) CE(8,9) CE(10,11) CE(12,13) CE(14,15)
  CE(0,2) CE(1,3) CE(4,6) CE(5,7) CE(8,10) CE(9,11) CE(12,14) CE(13,15)
  CE(1,2) CE(5,6) CE(9,10) CE(13,14)
  CE(0,4) CE(1,5) CE(2,6) CE(3,7) CE(8,12) CE(9,13) CE(10,14) CE(11,15)
  CE(2,4) CE(3,5) CE(10,12) CE(11,13)
  CE(1,2) CE(3,4) CE(5,6) CE(9,10) CE(11,12) CE(13,14)
  CE(0,8) CE(1,9) CE(2,10) CE(3,11) CE(4,12) CE(5,13) CE(6,14) CE(7,15)
  CE(4,8) CE(5,9) CE(6,10) CE(7,11)
  CE(2,4) CE(3,5) CE(6,8) CE(7,9) CE(10,12) CE(11,13)
  CE(1,2) CE(3,4) CE(5,6) CE(7,8) CE(9,10) CE(11,12) CE(13,14)
  #undef CE

  #pragma unroll
  for (int m = 0; m < 16; ++m){
    unsigned key = (unsigned)(sk[m] >> 4);
    unsigned slot = 15u - ((unsigned)sk[m] & 15u);
    lds[m*64 + lane] = ((unsigned long long)slot << 32) | (unsigned long long)key;
  }
  lds[16*64 + lane] = 0ull;
  lds[17*64 + lane] = 0ull;

  unsigned hk = (unsigned)(sk[0] >> 4); int hs = 15 - (int)((unsigned)sk[0] & 15u);
  unsigned nk = (unsigned)(sk[1] >> 4); int ns = 15 - (int)((unsigned)sk[1] & 15u);
  int p = 2;

  #pragma unroll
  for (int it = 0; it < KNN; ++it){
    unsigned g = wave_max_u32(hk);
    unsigned long long mask = __ballot(hk == g);
    int wl = __ffsll((long long)mask) - 1;
    int ws = __builtin_amdgcn_readlane(hs, wl);
    if (lane == 0) out[it] = wl*16 + ws;
    bool win = ((int)lane == wl);
    hk = win ? nk : hk;
    hs = win ? ns : hs;
    if (win){
      unsigned long long e = lds[p*64 + lane];
      nk = (unsigned)e; ns = (int)(e >> 32);
      p++;
    }
  }
}

// ============ fused topk + gather(+bf16 split, + chained norm) ============
template<bool EC1, int O, bool NRM>
__global__ __launch_bounds__(256) void k_topkg(
    const float* __restrict__ src,          // EC1 ? xt : D
    const float* __restrict__ UV, int ldUV,
    const float* __restrict__ gam, const float* __restrict__ bet,
    unsigned short* __restrict__ oh, unsigned short* __restrict__ ol, int ldo,
    float* __restrict__ nrm_out, const float* __restrict__ nrm_prev)
{
  __shared__ unsigned long long lds[4][18*64];
  __shared__ int idxs[4][KNN];
  int t = threadIdx.x, lane = t & 63, w = t >> 6;
  int row = blockIdx.x*4 + w;
  unsigned long long sk[16];
  if (EC1){
    int b = row >> 10, i0 = row & 1023;
    const float* base = src + (long)b*NPTS*3;
    float cx = base[i0*3], cy = base[i0*3+1], cz = base[i0*3+2];
    float pts[48];
    #pragma unroll
    for (int q = 0; q < 12; ++q)
      *(float4*)&pts[q*4] = *(const float4*)&base[lane*48 + q*4];
    #pragma unroll
    for (int m = 0; m < 16; ++m){
      float dx = pts[m*3]-cx, dy = pts[m*3+1]-cy, dz = pts[m*3+2]-cz;
      float d = -(dx*dx + dy*dy + dz*dz);
      sk[m] = ((unsigned long long)ordkey(d) << 4) | (unsigned long long)(15 - m);
    }
  } else {
    const float* Dr = src + (long)row*NPTS + lane*16;
    float v[16];
    #pragma unroll
    for (int q = 0; q < 4; ++q)
      *(float4*)&v[q*4] = *(const float4*)&Dr[q*4];
    #pragma unroll
    for (int m = 0; m < 16; ++m)
      sk[m] = ((unsigned long long)ordkey(v[m]) << 4) | (unsigned long long)(15 - m);
  }
  topk_select(sk, lds[w], idxs[w], lane);
  __syncthreads();

  // ---- gather phase: wave w -> point row ----
  int p = row;
  int b = p >> 10;
  const float* UVb = UV + (long)(b << 10)*ldUV;
  const float* UVp = UV + (long)p*ldUV;
  float sqsum = 0.f;

  if (O == 256){
    // vectorized: each lane owns 4 consecutive outputs (o0 = lane*4)
    int o0 = lane*4;
    float4 u4 = *(const float4*)&UVp[o0];
    float4 v4 = *(const float4*)&UVp[O + o0];
    float4 g4 = *(const float4*)&gam[o0];
    float4 be4 = *(const float4*)&bet[o0];
    float bx = v4.x-u4.x, by = v4.y-u4.y, bz = v4.z-u4.z, bw = v4.w-u4.w;
    float sx = g4.x*BNF, sy = g4.y*BNF, sz = g4.z*BNF, sw = g4.w*BNF;
    float b0 = -INFINITY, b1 = -INFINITY, b2 = -INFINITY, b3 = -INFINITY;
    #pragma unroll 4
    for (int k = 0; k < KNN; ++k){
      int j = idxs[w][k];
      float4 y4 = *(const float4*)&UVb[(long)j*ldUV + o0];
      b0 = fmaxf(b0, leakyf((y4.x + bx)*sx + be4.x));
      b1 = fmaxf(b1, leakyf((y4.y + by)*sy + be4.y));
      b2 = fmaxf(b2, leakyf((y4.z + bz)*sz + be4.z));
      b3 = fmaxf(b3, leakyf((y4.w + bw)*sw + be4.w));
    }
    long oo = (long)p*ldo + o0;
    unsigned short h0 = f2bf(b0), h1 = f2bf(b1), h2 = f2bf(b2), h3 = f2bf(b3);
    *(ushort4*)(oh + oo) = make_ushort4(h0, h1, h2, h3);
    *(ushort4*)(ol + oo) = make_ushort4(f2bf(b0 - bf2f(h0)), f2bf(b1 - bf2f(h1)),
                                        f2bf(b2 - bf2f(h2)), f2bf(b3 - bf2f(h3)));
    sqsum = b0*b0 + b1*b1 + b2*b2 + b3*b3;
  } else {
    #pragma unroll
    for (int jj = 0; jj < O/64; ++jj){
      int o = lane + jj*64;
      float uu = UVp[o];
      float vv = UVp[O + o];
      float base = vv - uu;
      float s = gam[o]*BNF, sh = bet[o];
      float best = -INFINITY;
      for (int k = 0; k < KNN; ++k){
        int j = idxs[w][k];
        float y = (UVb[(long)j*ldUV + o] + base)*s + sh;
        best = fmaxf(best, leakyf(y));
      }
      long oo = (long)p*ldo + o;
      unsigned short h = f2bf(best);
      oh[oo] = h;
      ol[oo] = f2bf(best - bf2f(h));
      sqsum += best*best;
    }
  }
  if (NRM){
    #pragma unroll
    for (int off = 32; off >= 1; off >>= 1) sqsum += __shfl_xor(sqsum, off, 64);
    if (lane == 0) nrm_out[p] = sqsum + (nrm_prev ? nrm_prev[p] : 0.f);
  }
}

// =====================================================================
// split-bf16 MFMA tile core, 32x32x16 shape, depth-2 counted-vmcnt pipe.
// Per wave: 2x2 frags of 32x32; k-slot mapping identical for A and B
// (k-permutation cancels in the dot product). C/D: col=lane&31,
// row=(reg&3)+8*(reg>>2)+4*(lane>>5)  [m74/m101-verified].
// =====================================================================
__device__ __forceinline__ void stage_tile(
    const unsigned short* __restrict__ pA0, const unsigned short* __restrict__ pA1, int lda,
    const unsigned short* __restrict__ pB0, const unsigned short* __restrict__ pB1, int ldb,
    int mt, int ot, int k0,
    unsigned short As[2][128*32], unsigned short Bs[2][128*32],
    int w, int r0, int q)
{
  #pragma unroll
  for (int half = 0; half < 2; ++half){
    int rowbase = w*16 + half*64;
    int row = rowbase + r0;
    int sq8 = (q ^ ((row >> 1) & 3)) * 8;       // pre-swizzled global slot
    gload_lds16(pA0 + (long)(mt+row)*lda + k0 + sq8, &As[0][rowbase*32]);
    gload_lds16(pA1 + (long)(mt+row)*lda + k0 + sq8, &As[1][rowbase*32]);
    gload_lds16(pB0 + (long)(ot+row)*ldb + k0 + sq8, &Bs[0][rowbase*32]);
    gload_lds16(pB1 + (long)(ot+row)*ldb + k0 + sq8, &Bs[1][rowbase*32]);
  }
}

__device__ __forceinline__ void gemm_tile(
    const unsigned short* __restrict__ pA0, const unsigned short* __restrict__ pA1, int lda,
    const unsigned short* __restrict__ pB0, const unsigned short* __restrict__ pB1, int ldb,
    int mt, int ot, int Ktot,
    unsigned short As[2][2][128*32], unsigned short Bs[2][2][128*32],
    f32x16 acc[2][2], int t)
{
  int lane = t & 63, w = t >> 6;
  int wm = w >> 1, wn = w & 1;
  int frow = lane & 31, kh = lane >> 5;
  int r0 = lane >> 2, q = lane & 3;

  int nsteps = Ktot >> 5;
  stage_tile(pA0,pA1,lda, pB0,pB1,ldb, mt,ot, 0,  As[0],Bs[0], w,r0,q);
  stage_tile(pA0,pA1,lda, pB0,pB1,ldb, mt,ot, 32, As[1],Bs[1], w,r0,q);

  for (int s = 0; s < nsteps; ++s){
    int cur = s & 1;
    if (s + 1 < nsteps) asm volatile("s_waitcnt vmcnt(8)" ::: "memory");
    else                asm volatile("s_waitcnt vmcnt(0)" ::: "memory");
    __builtin_amdgcn_s_barrier();           // all waves' buf[cur] ready
    __builtin_amdgcn_sched_barrier(0);

    bf16x8 af[2][2][2], bfr[2][2][2];       // [plane][mi|ni][ksub]
    #pragma unroll
    for (int pl = 0; pl < 2; ++pl){
      #pragma unroll
      for (int mi = 0; mi < 2; ++mi){
        int row = wm*64 + mi*32 + frow;
        #pragma unroll
        for (int ks = 0; ks < 2; ++ks)
          af[pl][mi][ks] = *(const bf16x8*)&As[cur][pl][row*32 + swz(ks*2 + kh, row)*8];
      }
      #pragma unroll
      for (int ni = 0; ni < 2; ++ni){
        int row = wn*64 + ni*32 + frow;
        #pragma unroll
        for (int ks = 0; ks < 2; ++ks)
          bfr[pl][ni][ks] = *(const bf16x8*)&Bs[cur][pl][row*32 + swz(ks*2 + kh, row)*8];
      }
    }
    asm volatile("s_waitcnt lgkmcnt(0)" ::: "memory");
    __builtin_amdgcn_sched_barrier(0);
    __builtin_amdgcn_s_barrier();           // all waves done reading buf[cur]
    __builtin_amdgcn_sched_barrier(0);

    if (s + 2 < nsteps)
      stage_tile(pA0,pA1,lda, pB0,pB1,ldb, mt,ot, (s+2)*32,
                 As[cur], Bs[cur], w,r0,q);

    #pragma unroll
    for (int mi = 0; mi < 2; ++mi){
      #pragma unroll
      for (int ni = 0; ni < 2; ++ni){
        #pragma unroll
        for (int ks = 0; ks < 2; ++ks){
          acc[mi][ni] = __builtin_amdgcn_mfma_f32_32x32x16_bf16(af[0][mi][ks], bfr[0][ni][ks], acc[mi][ni], 0, 0, 0);
          acc[mi][ni] = __builtin_amdgcn_mfma_f32_32x32x16_bf16(af[0][mi][ks], bfr[1][ni][ks], acc[mi][ni], 0, 0, 0);
          acc[mi][ni] = __builtin_amdgcn_mfma_f32_32x32x16_bf16(af[1][mi][ks], bfr[0][ni][ks], acc[mi][ni], 0, 0, 0);
        }
      }
    }
  }
}

// ============ combined distance (triangular+mirror) + UV projection ============
__global__ __launch_bounds__(256) void k_mgc(
    const unsigned short* __restrict__ Fh, const unsigned short* __restrict__ Fl,
    int ldf, long sFt,
    const unsigned short* __restrict__ Wh, const unsigned short* __restrict__ Wl,
    float* __restrict__ D, const float* __restrict__ nrm,
    float* __restrict__ UV, int ldUV, long sUV,
    int Ktot, int nDist)
{
  __shared__ unsigned short As[2][2][128*32];
  __shared__ unsigned short Bs[2][2][128*32];
  int b = blockIdx.z;
  int t = threadIdx.x;
  int lane = t & 63, w = t >> 6;
  int wm = w >> 1, wn = w & 1;
  int fcol = lane & 31;
  int hi4 = (lane >> 5) * 4;
  f32x16 acc[2][2] = {};
  const unsigned short* pA0 = Fh + (long)b*sFt;
  const unsigned short* pA1 = Fl + (long)b*sFt;

  if ((int)blockIdx.x < nDist){
    int u = blockIdx.x, r = 0;
    while (u >= 8 - r){ u -= 8 - r; ++r; }
    int mt = r*128, ot = (r + u)*128;
    gemm_tile(pA0, pA1, ldf, pA0, pA1, ldf, mt, ot, Ktot, As, Bs, acc, t);
    const float* nb = nrm + b*NPTS;
    float* ob = D + (long)b*NPTS*NPTS;
    bool mirror = (mt != ot);
    #pragma unroll
    for (int mi = 0; mi < 2; ++mi){
      #pragma unroll
      for (int ni = 0; ni < 2; ++ni){
        int gcol = ot + wn*64 + ni*32 + fcol;
        float nj = nb[gcol];
        #pragma unroll
        for (int rg = 0; rg < 4; ++rg){
          int grow0 = mt + wm*64 + mi*32 + rg*8 + hi4;
          float t0 = 2.f*acc[mi][ni][rg*4+0] - nb[grow0+0] - nj;
          float t1 = 2.f*acc[mi][ni][rg*4+1] - nb[grow0+1] - nj;
          float t2 = 2.f*acc[mi][ni][rg*4+2] - nb[grow0+2] - nj;
          float t3 = 2.f*acc[mi][ni][rg*4+3] - nb[grow0+3] - nj;
          ob[(long)(grow0+0)*NPTS + gcol] = t0;
          ob[(long)(grow0+1)*NPTS + gcol] = t1;
          ob[(long)(grow0+2)*NPTS + gcol] = t2;
          ob[(long)(grow0+3)*NPTS + gcol] = t3;
          if (mirror)
            *(float4*)&ob[(long)gcol*NPTS + grow0] = make_float4(t0, t1, t2, t3);
        }
      }
    }
  } else {
    int v = blockIdx.x - nDist;
    int mt = (v & 7)*128, ot = (v >> 3)*128;
    gemm_tile(pA0, pA1, ldf, Wh, Wl, Ktot, mt, ot, Ktot, As, Bs, acc, t);
    float* ob = UV + (long)b*sUV;
    #pragma unroll
    for (int mi = 0; mi < 2; ++mi){
      #pragma unroll
      for (int ni = 0; ni < 2; ++ni){
        int gcol = ot + wn*64 + ni*32 + fcol;
        #pragma unroll
        for (int rg = 0; rg < 4; ++rg){
          int grow0 = mt + wm*64 + mi*32 + rg*8 + hi4;
          #pragma unroll
          for (int rr = 0; rr < 4; ++rr)
            ob[(long)(grow0+rr)*ldUV + gcol] = acc[mi][ni][rg*4+rr];
        }
      }
    }
  }
}

// ============ combined pool projections (bn+leaky+max over points) ============
// pool2 (K=512) tiles first (blockIdx.x < 64) so the long blocks start earliest.
__global__ __launch_bounds__(256) void k_poolc(
    const unsigned short* __restrict__ A1h, const unsigned short* __restrict__ A1l,
    const unsigned short* __restrict__ B1h, const unsigned short* __restrict__ B1l,
    const float* __restrict__ gA, const float* __restrict__ bA, float* __restrict__ poolA,
    const unsigned short* __restrict__ A2h, const unsigned short* __restrict__ A2l,
    const unsigned short* __restrict__ B2h, const unsigned short* __restrict__ B2l,
    const float* __restrict__ gB, const float* __restrict__ bB, float* __restrict__ poolB)
{
  __shared__ unsigned short As[2][2][128*32];
  __shared__ unsigned short Bs[2][2][128*32];
  int b = blockIdx.z;
  int t = threadIdx.x;
  int lane = t & 63, w = t >> 6;
  int wn = w & 1;
  int fcol = lane & 31;
  bool second = (int)blockIdx.x < 64;          // pool2 first
  int v = second ? blockIdx.x : (blockIdx.x - 64);
  int mt = (v & 7)*128, ot = (v >> 3)*128;
  int K = second ? 512 : 128;
  const unsigned short* pA0 = (second ? A2h : A1h) + (long)b*NPTS*K;
  const unsigned short* pA1 = (second ? A2l : A1l) + (long)b*NPTS*K;
  const unsigned short* pB0 = second ? B2h : B1h;
  const unsigned short* pB1 = second ? B2l : B1l;
  const float* gam = second ? gB : gA;
  const float* bet = second ? bB : bA;
  float* pool = second ? poolB : poolA;

  f32x16 acc[2][2] = {};
  gemm_tile(pA0, pA1, K, pB0, pB1, K, mt, ot, K, As, Bs, acc, t);

  #pragma unroll
  for (int ni = 0; ni < 2; ++ni){
    int o = ot + wn*64 + ni*32 + fcol;
    float s = gam[o]*BNF, sh = bet[o];
    float mv = -INFINITY;
    #pragma unroll
    for (int mi = 0; mi < 2; ++mi){
      #pragma unroll
      for (int rg = 0; rg < 16; ++rg){
        float y = acc[mi][ni][rg]*s + sh;
        mv = fmaxf(mv, y >= 0.f ? y : 0.2f*y);
      }
    }
    mv = fmaxf(mv, __shfl_xor(mv, 32, 64));
    if (lane < 32) atomicMaxFloat(&pool[b*NPTS + o], mv);
  }
}

// ---------------- FC layers: one wave per output row, all 8 batches ----------------
__global__ void k_fc1(const float* __restrict__ p1, const float* __restrict__ p2,
                      const float* __restrict__ L1, const float* __restrict__ g6,
                      const float* __restrict__ b6, float* __restrict__ f1)
{
  int t = threadIdx.x;
  int lane = t & 63;
  int o = blockIdx.x*4 + (t >> 6);
  const float* w = L1 + (long)o*2048;
  float acc[BATCH] = {};
  for (int c0 = lane*4; c0 < 2048; c0 += 256){
    float4 wv = *(const float4*)(w + c0);
    const float* fb = (c0 < 1024) ? (p1 + c0) : (p2 + c0 - 1024);
    #pragma unroll
    for (int b = 0; b < BATCH; ++b){
      float4 fv = *(const float4*)(fb + b*1024);
      acc[b] += wv.x*fv.x + wv.y*fv.y + wv.z*fv.z + wv.w*fv.w;
    }
  }
  float s = g6[o]*BNF, sh = b6[o];
  #pragma unroll
  for (int b = 0; b < BATCH; ++b){
    float a = acc[b];
    #pragma unroll
    for (int off = 32; off >= 1; off >>= 1) a += __shfl_xor(a, off, 64);
    if (lane == b) f1[b*512 + o] = leakyf(a*s + sh);
  }
}

__global__ void k_fc2(const float* __restrict__ f1, const float* __restrict__ L2,
                      const float* __restrict__ bL2, const float* __restrict__ g7,
                      const float* __restrict__ b7, float* __restrict__ f2)
{
  int t = threadIdx.x;
  int lane = t & 63;
  int o = blockIdx.x*4 + (t >> 6);
  const float* w = L2 + (long)o*512 + lane*8;
  float4 w0 = *(const float4*)w;
  float4 w1 = *(const float4*)(w + 4);
  float s = g7[o]*BNF, sh = bL2[o]*g7[o]*BNF + b7[o];
  #pragma unroll
  for (int b = 0; b < BATCH; ++b){
    const float* fb = f1 + b*512 + lane*8;
    float4 f0 = *(const float4*)fb;
    float f1v0 = fb[4], f1v1 = fb[5], f1v2 = fb[6], f1v3 = fb[7];
    float a = w0.x*f0.x + w0.y*f0.y + w0.z*f0.z + w0.w*f0.w
            + w1.x*f1v0 + w1.y*f1v1 + w1.z*f1v2 + w1.w*f1v3;
    #pragma unroll
    for (int off = 32; off >= 1; off >>= 1) a += __shfl_xor(a, off, 64);
    if (lane == b) f2[b*256 + o] = leakyf(a*s + sh);
  }
}

__global__ void k_fc3(const float* __restrict__ f2, const float* __restrict__ L3,
                      const float* __restrict__ bL3, float* __restrict__ out)
{
  int lane = threadIdx.x;
  int o = blockIdx.x;
  float4 wv = *(const float4*)(L3 + (long)o*256 + lane*4);
  float bias = bL3[o];
  #pragma unroll
  for (int b = 0; b < BATCH; ++b){
    float4 fv = *(const float4*)(f2 + b*256 + lane*4);
    float a = wv.x*fv.x + wv.y*fv.y + wv.z*fv.z + wv.w*fv.w;
    #pragma unroll
    for (int off = 32; off >= 1; off >>= 1) a += __shfl_xor(a, off, 64);
    if (lane == b) out[b*40 + o] = a + bias;
  }
}

extern "C" void kernel_launch(void* const* d_in, const int* in_sizes, int n_in,
                              void* d_out, int out_size, void* d_ws, size_t ws_size,
                              hipStream_t stream) {
  const float* x   = (const float*)d_in[0];
  const float* W1  = (const float*)d_in[1];
  const float* g1  = (const float*)d_in[2];
  const float* b1  = (const float*)d_in[3];
  const float* W2  = (const float*)d_in[4];
  const float* g2  = (const float*)d_in[5];
  const float* b2  = (const float*)d_in[6];
  const float* W2m = (const float*)d_in[7];
  const float* g2m = (const float*)d_in[8];
  const float* b2m = (const float*)d_in[9];
  const float* W3  = (const float*)d_in[10];
  const float* g3  = (const float*)d_in[11];
  const float* b3  = (const float*)d_in[12];
  const float* W4  = (const float*)d_in[13];
  const float* g4  = (const float*)d_in[14];
  const float* b4  = (const float*)d_in[15];
  const float* W5  = (const float*)d_in[16];
  const float* g5  = (const float*)d_in[17];
  const float* b5  = (const float*)d_in[18];
  const float* L1  = (const float*)d_in[19];
  const float* g6  = (const float*)d_in[20];
  const float* b6  = (const float*)d_in[21];
  const float* L2  = (const float*)d_in[22];
  const float* bL2 = (const float*)d_in[23];
  const float* g7  = (const float*)d_in[24];
  const float* b7  = (const float*)d_in[25];
  const float* L3  = (const float*)d_in[26];
  const float* bL3 = (const float*)d_in[27];

  float* ws = (float*)d_ws;
  size_t off = 0;
  auto alloc = [&](size_t n)->float*{ float* p = ws + off; off += (n + 255) & ~(size_t)255; return p; };
  float* xt   = alloc((size_t)BATCH*NPTS*3);
  float* nrmA = alloc((size_t)BATCH*NPTS);
  float* nrmB = alloc((size_t)BATCH*NPTS);
  float* nrmC = alloc((size_t)BATCH*NPTS);
  float* D    = alloc((size_t)BATCH*NPTS*NPTS);
  float* UVbuf= alloc((size_t)BATCH*NPTS*512);
  float* p1   = alloc((size_t)BATCH*1024);
  float* p2   = alloc((size_t)BATCH*1024);
  float* f1   = alloc((size_t)BATCH*512);
  float* f2   = alloc((size_t)BATCH*256);

  auto ualloc = [&](size_t n_us)->unsigned short*{ return (unsigned short*)alloc((n_us + 1) / 2); };
  unsigned short* fh  = ualloc((size_t)BATCH*NPTS*128);
  unsigned short* fl  = ualloc((size_t)BATCH*NPTS*128);
  unsigned short* ch  = ualloc((size_t)BATCH*NPTS*512);
  unsigned short* cl  = ualloc((size_t)BATCH*NPTS*512);
  unsigned short* w2h = ualloc(128*64);
  unsigned short* w2l = ualloc(128*64);
  unsigned short* w3h = ualloc(512*128);
  unsigned short* w3l = ualloc(512*128);
  unsigned short* w4h = ualloc(512*256);
  unsigned short* w4l = ualloc(512*256);
  unsigned short* wmh = ualloc(1024*128);
  unsigned short* wml = ualloc(1024*128);
  unsigned short* w5h = ualloc(1024*512);
  unsigned short* w5l = ualloc(1024*512);

  if (off * sizeof(float) > ws_size) return;  // insufficient workspace -> fail loudly

  const long sF = (long)NPTS*128;
  const long sC = (long)NPTS*512;

  // 1. prep: weights, pool init, xt, EC1 U/V
  k_prep<<<4976, 256, 0, stream>>>(x, W1, W2, W3, W4, W2m, W5,
                                   w2h, w2l, w3h, w3l, w4h, w4l, wmh, wml, w5h, w5l,
                                   p1, p2, xt, UVbuf);

  // 2. EC1: fused dist(C=3)+topk+gather -> x1 (+nrmA)
  k_topkg<true,64,true><<<BATCH*NPTS/4, 256, 0, stream>>>(
      xt, UVbuf, 128, g1, b1, fh, fl, 128, nrmA, nullptr);

  // 3. EC2: dist(K=64, tri) + UV(K=64) combined
  k_mgc<<<dim3(44,1,BATCH), 256, 0, stream>>>(fh, fl, 128, sF, w2h, w2l,
                                              D, nrmA, UVbuf, 128, sF, 64, 36);
  // 4. EC2: topk+gather -> x2 (+nrmB chained)
  k_topkg<false,64,true><<<BATCH*NPTS/4, 256, 0, stream>>>(
      D, UVbuf, 128, g2, b2, fh + 64, fl + 64, 128, nrmB, nrmA);

  // 5. EC3: dist(K=128, tri) + UV(K=128) combined
  k_mgc<<<dim3(68,1,BATCH), 256, 0, stream>>>(fh, fl, 128, sF, w3h, w3l,
                                              D, nrmB, UVbuf, 512, sC, 128, 36);
  // 6. EC3: topk+gather -> x3 (+nrmC)
  k_topkg<false,256,true><<<BATCH*NPTS/4, 256, 0, stream>>>(
      D, UVbuf, 512, g3, b3, ch, cl, 512, nrmC, nullptr);

  // 7. EC4: dist(K=256, tri) + UV(K=256) combined
  k_mgc<<<dim3(68,1,BATCH), 256, 0, stream>>>(ch, cl, 512, sC, w4h, w4l,
                                              D, nrmC, UVbuf, 512, sC, 256, 36);
  // 8. EC4: topk+gather -> x4
  k_topkg<false,256,false><<<BATCH*NPTS/4, 256, 0, stream>>>(
      D, UVbuf, 512, g4, b4, ch + 256, cl + 256, 512, nullptr, nullptr);

  // 9. pools combined (pool2 K=512 first, then pool1 K=128)
  k_poolc<<<dim3(128,1,BATCH), 256, 0, stream>>>(
      fh, fl, wmh, wml, g2m, b2m, p1,
      ch, cl, w5h, w5l, g5, b5, p2);

  // 10-12. FC head
  k_fc1<<<128, 256, 0, stream>>>(p1, p2, L1, g6, b6, f1);
  k_fc2<<<64, 256, 0, stream>>>(f1, L2, bL2, g7, b7, f2);
  k_fc3<<<40, 64, 0, stream>>>(f2, L3, bL3, (float*)d_out);
}

// Round 16
// 229.779 us; speedup vs baseline: 1.0131x; 1.0131x over previous
//
#include <hip/hip_runtime.h>
#include <math.h>

#define BATCH 8
#define NPTS  1024
#define KNN   20
#define BNF   0.99999500003749937f  // 1/sqrt(1+1e-5)

typedef short bf16x8 __attribute__((ext_vector_type(8)));
typedef float f32x4  __attribute__((ext_vector_type(4)));

__device__ __forceinline__ float leakyf(float x){ return x >= 0.f ? x : 0.2f*x; }

__device__ __forceinline__ void atomicMaxFloat(float* addr, float val){
  if (val >= 0.f) atomicMax((int*)addr, __float_as_int(val));
  else            atomicMin((unsigned int*)addr, __float_as_uint(val));
}

__device__ __forceinline__ unsigned short f2bf(float x){
  unsigned u = __float_as_uint(x);
  unsigned r = (u + 0x7FFFu + ((u >> 16) & 1u)) >> 16;   // RNE (no NaN/inf in data)
  return (unsigned short)r;
}
__device__ __forceinline__ float bf2f(unsigned short h){
  return __uint_as_float(((unsigned)h) << 16);
}

// monotone f32 -> u32 key (exact order-preserving)
__device__ __forceinline__ unsigned ordkey(float x){
  unsigned u = __float_as_uint(x);
  unsigned mask = (unsigned)(((int)u) >> 31) | 0x80000000u;
  return u ^ mask;
}

// swizzled 16B-slot index within a 64B row (read side); write side pre-swizzles
// the GLOBAL source address so the LDS dest stays linear for global_load_lds.
__device__ __forceinline__ int swz(int q, int row){ return q ^ ((row >> 1) & 3); }

// async global->LDS, 16B per lane, dest = wave-uniform base + lane*16
__device__ __forceinline__ void gload_lds16(const void* g, void* l){
  __builtin_amdgcn_global_load_lds(
      (const __attribute__((address_space(1))) unsigned int*)g,
      (__attribute__((address_space(3))) unsigned int*)l, 16, 0, 0);
}

// =====================================================================
// k_prep: weight pack+split, pool init, x transpose, EC1 U/V projection.
// =====================================================================
__device__ __forceinline__ void split4store(float v0, float v1, float v2, float v3,
                                            unsigned short* hi, unsigned short* lo, long off){
  unsigned short h0=f2bf(v0), h1=f2bf(v1), h2=f2bf(v2), h3=f2bf(v3);
  *(ushort4*)(hi+off) = make_ushort4(h0,h1,h2,h3);
  *(ushort4*)(lo+off) = make_ushort4(f2bf(v0-bf2f(h0)), f2bf(v1-bf2f(h1)),
                                     f2bf(v2-bf2f(h2)), f2bf(v3-bf2f(h3)));
}

__global__ __launch_bounds__(256) void k_prep(
    const float* __restrict__ x,  const float* __restrict__ W1,
    const float* __restrict__ W2, const float* __restrict__ W3,
    const float* __restrict__ W4, const float* __restrict__ W2m,
    const float* __restrict__ W5,
    unsigned short* __restrict__ w2h, unsigned short* __restrict__ w2l,
    unsigned short* __restrict__ w3h, unsigned short* __restrict__ w3l,
    unsigned short* __restrict__ w4h, unsigned short* __restrict__ w4l,
    unsigned short* __restrict__ wmh, unsigned short* __restrict__ wml,
    unsigned short* __restrict__ w5h, unsigned short* __restrict__ w5l,
    float* __restrict__ p1, float* __restrict__ p2, float* __restrict__ xt,
    float* __restrict__ UV)
{
  int u = blockIdx.x*256 + threadIdx.x;
  if (u < 2048){                                   // S1: W2 pack+split
    int o = u >> 4, c = (u & 15) * 4;
    const float* s = (o < 64) ? (W2 + o*128 + c) : (W2 + (o-64)*128 + 64 + c);
    float4 v = *(const float4*)s;
    split4store(v.x,v.y,v.z,v.w, w2h,w2l, (long)o*64 + c);
    return;
  }
  u -= 2048;
  if (u < 16384){                                  // S2: W3 fold+split
    int o = u >> 5, c = (u & 31) * 4;
    const float* s = (o < 256) ? (W3 + o*512 + c) : (W3 + (o-256)*512 + 256 + c);
    float4 a = *(const float4*)s;
    float4 b = *(const float4*)(s + 128);
    split4store(a.x+b.x, a.y+b.y, a.z+b.z, a.w+b.w, w3h,w3l, (long)o*128 + c);
    return;
  }
  u -= 16384;
  if (u < 32768){                                  // S3: W4 pack+split
    int o = u >> 6, c = (u & 63) * 4;
    const float* s = (o < 256) ? (W4 + o*512 + c) : (W4 + (o-256)*512 + 256 + c);
    float4 v = *(const float4*)s;
    split4store(v.x,v.y,v.z,v.w, w4h,w4l, (long)o*256 + c);
    return;
  }
  u -= 32768;
  if (u < 32768){                                  // S4: W2m split
    int r = u >> 5, c = (u & 31) * 4;
    float4 v = *(const float4*)(W2m + (long)r*128 + c);
    split4store(v.x,v.y,v.z,v.w, wmh,wml, (long)r*128 + c);
    return;
  }
  u -= 32768;
  if (u < 131072){                                 // S5: W5 split
    int r = u >> 7, c = (u & 127) * 4;
    float4 v = *(const float4*)(W5 + (long)r*512 + c);
    split4store(v.x,v.y,v.z,v.w, w5h,w5l, (long)r*512 + c);
    return;
  }
  u -= 131072;
  if (u < 4096){                                   // S6: pool init
    float4 ninf = make_float4(-INFINITY,-INFINITY,-INFINITY,-INFINITY);
    if (u < 2048) *(float4*)(p1 + u*4) = ninf;
    else          *(float4*)(p2 + (u-2048)*4) = ninf;
    return;
  }
  u -= 4096;
  if (u < 6144){                                   // S7: transpose x -> xt
    int b = u / 768, rem = u % 768;
    int c = rem >> 8, n0 = (rem & 255) * 4;
    float4 v = *(const float4*)(x + ((long)b*3 + c)*NPTS + n0);
    float* o = xt + (long)b*NPTS*3;
    o[(n0+0)*3 + c] = v.x; o[(n0+1)*3 + c] = v.y;
    o[(n0+2)*3 + c] = v.z; o[(n0+3)*3 + c] = v.w;
    return;
  }
  u -= 6144;
  {                                                // S8: EC1 U/V from x directly
    int p = u >> 7, o = u & 127;
    int b = p >> 10, n = p & 1023;
    const float* xb = x + (long)b*3*NPTS + n;
    float x0 = xb[0], x1 = xb[NPTS], x2 = xb[2*NPTS];
    const float* w = (o < 64) ? (W1 + o*6) : (W1 + (o-64)*6 + 3);
    UV[(long)p*128 + o] = w[0]*x0 + w[1]*x1 + w[2]*x2;
  }
}

// ================= top-20 selection (exact: value desc, index asc) =================
__device__ __forceinline__ unsigned wave_max_u32(unsigned x){
  unsigned t;
  t = (unsigned)__builtin_amdgcn_update_dpp((int)x, (int)x, 0x111, 0xf, 0xf, false); x = x > t ? x : t;
  t = (unsigned)__builtin_amdgcn_update_dpp((int)x, (int)x, 0x112, 0xf, 0xf, false); x = x > t ? x : t;
  t = (unsigned)__builtin_amdgcn_update_dpp((int)x, (int)x, 0x114, 0xf, 0xf, false); x = x > t ? x : t;
  t = (unsigned)__builtin_amdgcn_update_dpp((int)x, (int)x, 0x118, 0xf, 0xf, false); x = x > t ? x : t;
  t = (unsigned)__builtin_amdgcn_update_dpp((int)x, (int)x, 0x142, 0xa, 0xf, false); x = x > t ? x : t;
  t = (unsigned)__builtin_amdgcn_update_dpp((int)x, (int)x, 0x143, 0xc, 0xf, false); x = x > t ? x : t;
  return (unsigned)__builtin_amdgcn_readlane((int)x, 63);
}

__device__ __forceinline__ void topk_select(unsigned long long* sk,
                                            unsigned long long* lds,
                                            int* out, int lane)
{
  #define CE(a,b) { unsigned long long ka=sk[a], kb=sk[b]; bool sw=ka<kb; sk[a]=sw?kb:ka; sk[b]=sw?ka:kb; }
  CE(0,1) CE(2,3) CE(4,5) CE(6,7) CE(8,9) CE(10,11) CE(12,13) CE(14,15)
  CE(0,2) CE(1,3) CE(4,6) CE(5,7) CE(8,10) CE(9,11) CE(12,14) CE(13,15)
  CE(1,2) CE(5,6) CE(9,10) CE(13,14)
  CE(0,4) CE(1,5) CE(2,6) CE(3,7) CE(8,12) CE(9,13) CE(10,14) CE(11,15)
  CE(2,4) CE(3,5) CE(10,12) CE(11,13)
  CE(1,2) CE(3,4) CE(5,6) CE(9,10) CE(11,12) CE(13,14)
  CE(0,8) CE(1,9) CE(2,10) CE(3,11) CE(4,12) CE(5,13) CE(6,14) CE(7,15)
  CE(4,8) CE(5,9) CE(6,10) CE(7,11)
  CE(2,4) CE(3,5) CE(6,8) CE(7,9) CE(10,12) CE(11,13)
  CE(1,2) CE(3,4) CE(5,6) CE(7,8) CE(9,10) CE(11,12) CE(13,14)
  #undef CE

  #pragma unroll
  for (int m = 0; m < 16; ++m){
    unsigned key = (unsigned)(sk[m] >> 4);
    unsigned slot = 15u - ((unsigned)sk[m] & 15u);
    lds[m*64 + lane] = ((unsigned long long)slot << 32) | (unsigned long long)key;
  }
  lds[16*64 + lane] = 0ull;
  lds[17*64 + lane] = 0ull;

  unsigned hk = (unsigned)(sk[0] >> 4); int hs = 15 - (int)((unsigned)sk[0] & 15u);
  unsigned nk = (unsigned)(sk[1] >> 4); int ns = 15 - (int)((unsigned)sk[1] & 15u);
  int p = 2;

  #pragma unroll
  for (int it = 0; it < KNN; ++it){
    unsigned g = wave_max_u32(hk);
    unsigned long long mask = __ballot(hk == g);
    int wl = __ffsll((long long)mask) - 1;
    int ws = __builtin_amdgcn_readlane(hs, wl);
    if (lane == 0) out[it] = wl*16 + ws;
    bool win = ((int)lane == wl);
    hk = win ? nk : hk;
    hs = win ? ns : hs;
    if (win){
      unsigned long long e = lds[p*64 + lane];
      nk = (unsigned)e; ns = (int)(e >> 32);
      p++;
    }
  }
}

// ============ fused topk + gather(+bf16 split, + chained norm) ============
template<bool EC1, int O, bool NRM>
__global__ __launch_bounds__(256) void k_topkg(
    const float* __restrict__ src,          // EC1 ? xt : D
    const float* __restrict__ UV, int ldUV,
    const float* __restrict__ gam, const float* __restrict__ bet,
    unsigned short* __restrict__ oh, unsigned short* __restrict__ ol, int ldo,
    float* __restrict__ nrm_out, const float* __restrict__ nrm_prev)
{
  __shared__ unsigned long long lds[4][18*64];
  __shared__ int idxs[4][KNN];
  int t = threadIdx.x, lane = t & 63, w = t >> 6;
  int row = blockIdx.x*4 + w;
  unsigned long long sk[16];
  if (EC1){
    int b = row >> 10, i0 = row & 1023;
    const float* base = src + (long)b*NPTS*3;
    float cx = base[i0*3], cy = base[i0*3+1], cz = base[i0*3+2];
    float pts[48];
    #pragma unroll
    for (int q = 0; q < 12; ++q)
      *(float4*)&pts[q*4] = *(const float4*)&base[lane*48 + q*4];
    #pragma unroll
    for (int m = 0; m < 16; ++m){
      float dx = pts[m*3]-cx, dy = pts[m*3+1]-cy, dz = pts[m*3+2]-cz;
      float d = -(dx*dx + dy*dy + dz*dz);
      sk[m] = ((unsigned long long)ordkey(d) << 4) | (unsigned long long)(15 - m);
    }
  } else {
    const float* Dr = src + (long)row*NPTS + lane*16;
    float v[16];
    #pragma unroll
    for (int q = 0; q < 4; ++q)
      *(float4*)&v[q*4] = *(const float4*)&Dr[q*4];
    #pragma unroll
    for (int m = 0; m < 16; ++m)
      sk[m] = ((unsigned long long)ordkey(v[m]) << 4) | (unsigned long long)(15 - m);
  }
  topk_select(sk, lds[w], idxs[w], lane);
  __syncthreads();

  // ---- gather phase: wave w -> point row ----
  int p = row;
  int b = p >> 10;
  const float* UVb = UV + (long)(b << 10)*ldUV;
  const float* UVp = UV + (long)p*ldUV;
  float sqsum = 0.f;

  if (O == 256){
    // vectorized: each lane owns 4 consecutive outputs (o0 = lane*4)
    int o0 = lane*4;
    float4 u4 = *(const float4*)&UVp[o0];
    float4 v4 = *(const float4*)&UVp[O + o0];
    float4 g4 = *(const float4*)&gam[o0];
    float4 be4 = *(const float4*)&bet[o0];
    float bx = v4.x-u4.x, by = v4.y-u4.y, bz = v4.z-u4.z, bw = v4.w-u4.w;
    float sx = g4.x*BNF, sy = g4.y*BNF, sz = g4.z*BNF, sw = g4.w*BNF;
    float b0 = -INFINITY, b1 = -INFINITY, b2 = -INFINITY, b3 = -INFINITY;
    #pragma unroll 4
    for (int k = 0; k < KNN; ++k){
      int j = idxs[w][k];
      float4 y4 = *(const float4*)&UVb[(long)j*ldUV + o0];
      b0 = fmaxf(b0, leakyf((y4.x + bx)*sx + be4.x));
      b1 = fmaxf(b1, leakyf((y4.y + by)*sy + be4.y));
      b2 = fmaxf(b2, leakyf((y4.z + bz)*sz + be4.z));
      b3 = fmaxf(b3, leakyf((y4.w + bw)*sw + be4.w));
    }
    long oo = (long)p*ldo + o0;
    unsigned short h0 = f2bf(b0), h1 = f2bf(b1), h2 = f2bf(b2), h3 = f2bf(b3);
    *(ushort4*)(oh + oo) = make_ushort4(h0, h1, h2, h3);
    *(ushort4*)(ol + oo) = make_ushort4(f2bf(b0 - bf2f(h0)), f2bf(b1 - bf2f(h1)),
                                        f2bf(b2 - bf2f(h2)), f2bf(b3 - bf2f(h3)));
    sqsum = b0*b0 + b1*b1 + b2*b2 + b3*b3;
  } else {
    #pragma unroll
    for (int jj = 0; jj < O/64; ++jj){
      int o = lane + jj*64;
      float uu = UVp[o];
      float vv = UVp[O + o];
      float base = vv - uu;
      float s = gam[o]*BNF, sh = bet[o];
      float best = -INFINITY;
      for (int k = 0; k < KNN; ++k){
        int j = idxs[w][k];
        float y = (UVb[(long)j*ldUV + o] + base)*s + sh;
        best = fmaxf(best, leakyf(y));
      }
      long oo = (long)p*ldo + o;
      unsigned short h = f2bf(best);
      oh[oo] = h;
      ol[oo] = f2bf(best - bf2f(h));
      sqsum += best*best;
    }
  }
  if (NRM){
    #pragma unroll
    for (int off = 32; off >= 1; off >>= 1) sqsum += __shfl_xor(sqsum, off, 64);
    if (lane == 0) nrm_out[p] = sqsum + (nrm_prev ? nrm_prev[p] : 0.f);
  }
}

// =====================================================================
// split-bf16 MFMA tile core (16x16x32), depth-2 pipeline, COUNTED vmcnt.
// =====================================================================
__device__ __forceinline__ void stage_tile(
    const unsigned short* __restrict__ pA0, const unsigned short* __restrict__ pA1, int lda,
    const unsigned short* __restrict__ pB0, const unsigned short* __restrict__ pB1, int ldb,
    int mt, int ot, int k0,
    unsigned short As[2][128*32], unsigned short Bs[2][128*32],
    int w, int r0, int q)
{
  #pragma unroll
  for (int half = 0; half < 2; ++half){
    int rowbase = w*16 + half*64;
    int row = rowbase + r0;
    int sq8 = (q ^ ((row >> 1) & 3)) * 8;       // pre-swizzled global slot
    gload_lds16(pA0 + (long)(mt+row)*lda + k0 + sq8, &As[0][rowbase*32]);
    gload_lds16(pA1 + (long)(mt+row)*lda + k0 + sq8, &As[1][rowbase*32]);
    gload_lds16(pB0 + (long)(ot+row)*ldb + k0 + sq8, &Bs[0][rowbase*32]);
    gload_lds16(pB1 + (long)(ot+row)*ldb + k0 + sq8, &Bs[1][rowbase*32]);
  }
}

__device__ __forceinline__ void gemm_tile(
    const unsigned short* __restrict__ pA0, const unsigned short* __restrict__ pA1, int lda,
    const unsigned short* __restrict__ pB0, const unsigned short* __restrict__ pB1, int ldb,
    int mt, int ot, int Ktot,
    unsigned short As[2][2][128*32], unsigned short Bs[2][2][128*32],
    f32x4 acc[4][4], int t)
{
  int lane = t & 63, w = t >> 6;
  int wm = w >> 1, wn = w & 1;
  int frow = lane & 15, kg = lane >> 4;
  int r0 = lane >> 2, q = lane & 3;

  int nsteps = Ktot >> 5;
  stage_tile(pA0,pA1,lda, pB0,pB1,ldb, mt,ot, 0,  As[0],Bs[0], w,r0,q);
  stage_tile(pA0,pA1,lda, pB0,pB1,ldb, mt,ot, 32, As[1],Bs[1], w,r0,q);

  for (int s = 0; s < nsteps; ++s){
    int cur = s & 1;
    if (s + 1 < nsteps) asm volatile("s_waitcnt vmcnt(8)" ::: "memory");
    else                asm volatile("s_waitcnt vmcnt(0)" ::: "memory");
    __builtin_amdgcn_s_barrier();           // all waves' buf[cur] ready
    __builtin_amdgcn_sched_barrier(0);

    bf16x8 af[2][4], bfr[2][4];
    #pragma unroll
    for (int pl = 0; pl < 2; ++pl){
      #pragma unroll
      for (int mi = 0; mi < 4; ++mi){
        int row = wm*64 + mi*16 + frow;
        af[pl][mi] = *(const bf16x8*)&As[cur][pl][row*32 + swz(kg, row)*8];
      }
      #pragma unroll
      for (int ni = 0; ni < 4; ++ni){
        int row = wn*64 + ni*16 + frow;
        bfr[pl][ni] = *(const bf16x8*)&Bs[cur][pl][row*32 + swz(kg, row)*8];
      }
    }
    asm volatile("s_waitcnt lgkmcnt(0)" ::: "memory");  // my reads landed in regs
    __builtin_amdgcn_sched_barrier(0);
    __builtin_amdgcn_s_barrier();           // all waves done reading buf[cur]
    __builtin_amdgcn_sched_barrier(0);

    if (s + 2 < nsteps)                     // overwrite buf[cur] with step s+2
      stage_tile(pA0,pA1,lda, pB0,pB1,ldb, mt,ot, (s+2)*32,
                 As[cur], Bs[cur], w,r0,q);

    #pragma unroll
    for (int mi = 0; mi < 4; ++mi){
      #pragma unroll
      for (int ni = 0; ni < 4; ++ni){
        acc[mi][ni] = __builtin_amdgcn_mfma_f32_16x16x32_bf16(af[0][mi], bfr[0][ni], acc[mi][ni], 0, 0, 0);
        acc[mi][ni] = __builtin_amdgcn_mfma_f32_16x16x32_bf16(af[0][mi], bfr[1][ni], acc[mi][ni], 0, 0, 0);
        acc[mi][ni] = __builtin_amdgcn_mfma_f32_16x16x32_bf16(af[1][mi], bfr[0][ni], acc[mi][ni], 0, 0, 0);
      }
    }
  }
}

// ============ combined distance (triangular+mirror) + UV projection ============
__global__ __launch_bounds__(256) void k_mgc(
    const unsigned short* __restrict__ Fh, const unsigned short* __restrict__ Fl,
    int ldf, long sFt,
    const unsigned short* __restrict__ Wh, const unsigned short* __restrict__ Wl,
    float* __restrict__ D, const float* __restrict__ nrm,
    float* __restrict__ UV, int ldUV, long sUV,
    int Ktot, int nDist)
{
  __shared__ unsigned short As[2][2][128*32];
  __shared__ unsigned short Bs[2][2][128*32];
  int b = blockIdx.z;
  int t = threadIdx.x;
  int lane = t & 63, w = t >> 6;
  int wm = w >> 1, wn = w & 1;
  int frow = lane & 15, kg = lane >> 4;
  f32x4 acc[4][4] = {};
  const unsigned short* pA0 = Fh + (long)b*sFt;
  const unsigned short* pA1 = Fl + (long)b*sFt;

  if ((int)blockIdx.x < nDist){
    int u = blockIdx.x, r = 0;
    while (u >= 8 - r){ u -= 8 - r; ++r; }
    int mt = r*128, ot = (r + u)*128;
    gemm_tile(pA0, pA1, ldf, pA0, pA1, ldf, mt, ot, Ktot, As, Bs, acc, t);
    const float* nb = nrm + b*NPTS;
    float* ob = D + (long)b*NPTS*NPTS;
    bool mirror = (mt != ot);
    #pragma unroll
    for (int mi = 0; mi < 4; ++mi){
      int grow0 = mt + wm*64 + mi*16 + kg*4;
      float n0 = nb[grow0], n1 = nb[grow0+1], n2 = nb[grow0+2], n3 = nb[grow0+3];
      #pragma unroll
      for (int ni = 0; ni < 4; ++ni){
        int gcol = ot + wn*64 + ni*16 + frow;
        float nj = nb[gcol];
        float t0 = 2.f*acc[mi][ni][0] - n0 - nj;
        float t1 = 2.f*acc[mi][ni][1] - n1 - nj;
        float t2 = 2.f*acc[mi][ni][2] - n2 - nj;
        float t3 = 2.f*acc[mi][ni][3] - n3 - nj;
        ob[(long)(grow0+0)*NPTS + gcol] = t0;
        ob[(long)(grow0+1)*NPTS + gcol] = t1;
        ob[(long)(grow0+2)*NPTS + gcol] = t2;
        ob[(long)(grow0+3)*NPTS + gcol] = t3;
        if (mirror)
          *(float4*)&ob[(long)gcol*NPTS + grow0] = make_float4(t0, t1, t2, t3);
      }
    }
  } else {
    int v = blockIdx.x - nDist;
    int mt = (v & 7)*128, ot = (v >> 3)*128;
    gemm_tile(pA0, pA1, ldf, Wh, Wl, Ktot, mt, ot, Ktot, As, Bs, acc, t);
    float* ob = UV + (long)b*sUV;
    #pragma unroll
    for (int mi = 0; mi < 4; ++mi){
      int grow0 = mt + wm*64 + mi*16 + kg*4;
      #pragma unroll
      for (int ni = 0; ni < 4; ++ni){
        int gcol = ot + wn*64 + ni*16 + frow;
        #pragma unroll
        for (int j = 0; j < 4; ++j)
          ob[(long)(grow0+j)*ldUV + gcol] = acc[mi][ni][j];
      }
    }
  }
}

// ============ combined pool projections (bn+leaky+max over points) ============
// pool2 (K=512) tiles first (blockIdx.x < 64) so the long blocks start earliest.
__global__ __launch_bounds__(256) void k_poolc(
    const unsigned short* __restrict__ A1h, const unsigned short* __restrict__ A1l,
    const unsigned short* __restrict__ B1h, const unsigned short* __restrict__ B1l,
    const float* __restrict__ gA, const float* __restrict__ bA, float* __restrict__ poolA,
    const unsigned short* __restrict__ A2h, const unsigned short* __restrict__ A2l,
    const unsigned short* __restrict__ B2h, const unsigned short* __restrict__ B2l,
    const float* __restrict__ gB, const float* __restrict__ bB, float* __restrict__ poolB)
{
  __shared__ unsigned short As[2][2][128*32];
  __shared__ unsigned short Bs[2][2][128*32];
  int b = blockIdx.z;
  int t = threadIdx.x;
  int lane = t & 63, w = t >> 6;
  int wn = w & 1;
  int frow = lane & 15;
  bool second = (int)blockIdx.x < 64;          // pool2 first
  int v = second ? blockIdx.x : (blockIdx.x - 64);
  int mt = (v & 7)*128, ot = (v >> 3)*128;
  int K = second ? 512 : 128;
  const unsigned short* pA0 = (second ? A2h : A1h) + (long)b*NPTS*K;
  const unsigned short* pA1 = (second ? A2l : A1l) + (long)b*NPTS*K;
  const unsigned short* pB0 = second ? B2h : B1h;
  const unsigned short* pB1 = second ? B2l : B1l;
  const float* gam = second ? gB : gA;
  const float* bet = second ? bB : bA;
  float* pool = second ? poolB : poolA;

  f32x4 acc[4][4] = {};
  gemm_tile(pA0, pA1, K, pB0, pB1, K, mt, ot, K, As, Bs, acc, t);

  #pragma unroll
  for (int ni = 0; ni < 4; ++ni){
    int o = ot + wn*64 + ni*16 + frow;
    float s = gam[o]*BNF, sh = bet[o];
    float mv = -INFINITY;
    #pragma unroll
    for (int mi = 0; mi < 4; ++mi){
      #pragma unroll
      for (int j = 0; j < 4; ++j){
        float y = acc[mi][ni][j]*s + sh;
        mv = fmaxf(mv, y >= 0.f ? y : 0.2f*y);
      }
    }
    mv = fmaxf(mv, __shfl_xor(mv, 16, 64));
    mv = fmaxf(mv, __shfl_xor(mv, 32, 64));
    if (lane < 16) atomicMaxFloat(&pool[b*NPTS + o], mv);
  }
}

// ---------------- FC layers: one wave per output row, all 8 batches ----------------
__global__ void k_fc1(const float* __restrict__ p1, const float* __restrict__ p2,
                      const float* __restrict__ L1, const float* __restrict__ g6,
                      const float* __restrict__ b6, float* __restrict__ f1)
{
  int t = threadIdx.x;
  int lane = t & 63;
  int o = blockIdx.x*4 + (t >> 6);
  const float* w = L1 + (long)o*2048;
  float acc[BATCH] = {};
  for (int c0 = lane*4; c0 < 2048; c0 += 256){
    float4 wv = *(const float4*)(w + c0);
    const float* fb = (c0 < 1024) ? (p1 + c0) : (p2 + c0 - 1024);
    #pragma unroll
    for (int b = 0; b < BATCH; ++b){
      float4 fv = *(const float4*)(fb + b*1024);
      acc[b] += wv.x*fv.x + wv.y*fv.y + wv.z*fv.z + wv.w*fv.w;
    }
  }
  float s = g6[o]*BNF, sh = b6[o];
  #pragma unroll
  for (int b = 0; b < BATCH; ++b){
    float a = acc[b];
    #pragma unroll
    for (int off = 32; off >= 1; off >>= 1) a += __shfl_xor(a, off, 64);
    if (lane == b) f1[b*512 + o] = leakyf(a*s + sh);
  }
}

__global__ void k_fc2(const float* __restrict__ f1, const float* __restrict__ L2,
                      const float* __restrict__ bL2, const float* __restrict__ g7,
                      const float* __restrict__ b7, float* __restrict__ f2)
{
  int t = threadIdx.x;
  int lane = t & 63;
  int o = blockIdx.x*4 + (t >> 6);
  const float* w = L2 + (long)o*512 + lane*8;
  float4 w0 = *(const float4*)w;
  float4 w1 = *(const float4*)(w + 4);
  float s = g7[o]*BNF, sh = bL2[o]*g7[o]*BNF + b7[o];
  #pragma unroll
  for (int b = 0; b < BATCH; ++b){
    const float* fb = f1 + b*512 + lane*8;
    float4 f0 = *(const float4*)fb;
    float f1v0 = fb[4], f1v1 = fb[5], f1v2 = fb[6], f1v3 = fb[7];
    float a = w0.x*f0.x + w0.y*f0.y + w0.z*f0.z + w0.w*f0.w
            + w1.x*f1v0 + w1.y*f1v1 + w1.z*f1v2 + w1.w*f1v3;
    #pragma unroll
    for (int off = 32; off >= 1; off >>= 1) a += __shfl_xor(a, off, 64);
    if (lane == b) f2[b*256 + o] = leakyf(a*s + sh);
  }
}

__global__ void k_fc3(const float* __restrict__ f2, const float* __restrict__ L3,
                      const float* __restrict__ bL3, float* __restrict__ out)
{
  int lane = threadIdx.x;
  int o = blockIdx.x;
  float4 wv = *(const float4*)(L3 + (long)o*256 + lane*4);
  float bias = bL3[o];
  #pragma unroll
  for (int b = 0; b < BATCH; ++b){
    float4 fv = *(const float4*)(f2 + b*256 + lane*4);
    float a = wv.x*fv.x + wv.y*fv.y + wv.z*fv.z + wv.w*fv.w;
    #pragma unroll
    for (int off = 32; off >= 1; off >>= 1) a += __shfl_xor(a, off, 64);
    if (lane == b) out[b*40 + o] = a + bias;
  }
}

extern "C" void kernel_launch(void* const* d_in, const int* in_sizes, int n_in,
                              void* d_out, int out_size, void* d_ws, size_t ws_size,
                              hipStream_t stream) {
  const float* x   = (const float*)d_in[0];
  const float* W1  = (const float*)d_in[1];
  const float* g1  = (const float*)d_in[2];
  const float* b1  = (const float*)d_in[3];
  const float* W2  = (const float*)d_in[4];
  const float* g2  = (const float*)d_in[5];
  const float* b2  = (const float*)d_in[6];
  const float* W2m = (const float*)d_in[7];
  const float* g2m = (const float*)d_in[8];
  const float* b2m = (const float*)d_in[9];
  const float* W3  = (const float*)d_in[10];
  const float* g3  = (const float*)d_in[11];
  const float* b3  = (const float*)d_in[12];
  const float* W4  = (const float*)d_in[13];
  const float* g4  = (const float*)d_in[14];
  const float* b4  = (const float*)d_in[15];
  const float* W5  = (const float*)d_in[16];
  const float* g5  = (const float*)d_in[17];
  const float* b5  = (const float*)d_in[18];
  const float* L1  = (const float*)d_in[19];
  const float* g6  = (const float*)d_in[20];
  const float* b6  = (const float*)d_in[21];
  const float* L2  = (const float*)d_in[22];
  const float* bL2 = (const float*)d_in[23];
  const float* g7  = (const float*)d_in[24];
  const float* b7  = (const float*)d_in[25];
  const float* L3  = (const float*)d_in[26];
  const float* bL3 = (const float*)d_in[27];

  float* ws = (float*)d_ws;
  size_t off = 0;
  auto alloc = [&](size_t n)->float*{ float* p = ws + off; off += (n + 255) & ~(size_t)255; return p; };
  float* xt   = alloc((size_t)BATCH*NPTS*3);
  float* nrmA = alloc((size_t)BATCH*NPTS);
  float* nrmB = alloc((size_t)BATCH*NPTS);
  float* nrmC = alloc((size_t)BATCH*NPTS);
  float* D    = alloc((size_t)BATCH*NPTS*NPTS);
  float* UVbuf= alloc((size_t)BATCH*NPTS*512);
  float* p1   = alloc((size_t)BATCH*1024);
  float* p2   = alloc((size_t)BATCH*1024);
  float* f1   = alloc((size_t)BATCH*512);
  float* f2   = alloc((size_t)BATCH*256);

  auto ualloc = [&](size_t n_us)->unsigned short*{ return (unsigned short*)alloc((n_us + 1) / 2); };
  unsigned short* fh  = ualloc((size_t)BATCH*NPTS*128);
  unsigned short* fl  = ualloc((size_t)BATCH*NPTS*128);
  unsigned short* ch  = ualloc((size_t)BATCH*NPTS*512);
  unsigned short* cl  = ualloc((size_t)BATCH*NPTS*512);
  unsigned short* w2h = ualloc(128*64);
  unsigned short* w2l = ualloc(128*64);
  unsigned short* w3h = ualloc(512*128);
  unsigned short* w3l = ualloc(512*128);
  unsigned short* w4h = ualloc(512*256);
  unsigned short* w4l = ualloc(512*256);
  unsigned short* wmh = ualloc(1024*128);
  unsigned short* wml = ualloc(1024*128);
  unsigned short* w5h = ualloc(1024*512);
  unsigned short* w5l = ualloc(1024*512);

  if (off * sizeof(float) > ws_size) return;  // insufficient workspace -> fail loudly

  const long sF = (long)NPTS*128;
  const long sC = (long)NPTS*512;

  // 1. prep: weights, pool init, xt, EC1 U/V
  k_prep<<<4976, 256, 0, stream>>>(x, W1, W2, W3, W4, W2m, W5,
                                   w2h, w2l, w3h, w3l, w4h, w4l, wmh, wml, w5h, w5l,
                                   p1, p2, xt, UVbuf);

  // 2. EC1: fused dist(C=3)+topk+gather -> x1 (+nrmA)
  k_topkg<true,64,true><<<BATCH*NPTS/4, 256, 0, stream>>>(
      xt, UVbuf, 128, g1, b1, fh, fl, 128, nrmA, nullptr);

  // 3. EC2: dist(K=64, tri) + UV(K=64) combined
  k_mgc<<<dim3(44,1,BATCH), 256, 0, stream>>>(fh, fl, 128, sF, w2h, w2l,
                                              D, nrmA, UVbuf, 128, sF, 64, 36);
  // 4. EC2: topk+gather -> x2 (+nrmB chained)
  k_topkg<false,64,true><<<BATCH*NPTS/4, 256, 0, stream>>>(
      D, UVbuf, 128, g2, b2, fh + 64, fl + 64, 128, nrmB, nrmA);

  // 5. EC3: dist(K=128, tri) + UV(K=128) combined
  k_mgc<<<dim3(68,1,BATCH), 256, 0, stream>>>(fh, fl, 128, sF, w3h, w3l,
                                              D, nrmB, UVbuf, 512, sC, 128, 36);
  // 6. EC3: topk+gather -> x3 (+nrmC)
  k_topkg<false,256,true><<<BATCH*NPTS/4, 256, 0, stream>>>(
      D, UVbuf, 512, g3, b3, ch, cl, 512, nrmC, nullptr);

  // 7. EC4: dist(K=256, tri) + UV(K=256) combined
  k_mgc<<<dim3(68,1,BATCH), 256, 0, stream>>>(ch, cl, 512, sC, w4h, w4l,
                                              D, nrmC, UVbuf, 512, sC, 256, 36);
  // 8. EC4: topk+gather -> x4
  k_topkg<false,256,false><<<BATCH*NPTS/4, 256, 0, stream>>>(
      D, UVbuf, 512, g4, b4, ch + 256, cl + 256, 512, nullptr, nullptr);

  // 9. pools combined (pool2 K=512 first, then pool1 K=128)
  k_poolc<<<dim3(128,1,BATCH), 256, 0, stream>>>(
      fh, fl, wmh, wml, g2m, b2m, p1,
      ch, cl, w5h, w5l, g5, b5, p2);

  // 10-12. FC head
  k_fc1<<<128, 256, 0, stream>>>(p1, p2, L1, g6, b6, f1);
  k_fc2<<<64, 256, 0, stream>>>(f1, L2, bL2, g7, b7, f2);
  k_fc3<<<40, 64, 0, stream>>>(f2, L3, bL3, (float*)d_out);
}